// Round 1
// baseline (1893.498 us; speedup 1.0000x reference)
//
#include <hip/hip_runtime.h>
#include <math.h>

// Problem constants (from reference): N=8192 rows, C=32000 classes, fp32.
#define N_ROWS 8192
#define C_COLS 32000
#define C4     (C_COLS / 4)   // 8000 float4 per row

// One block per row. 256 threads, float4 strided loads (coalesced).
// Online-softmax single pass: per-thread running (m, s) plus dot=sum(t*x),
// ts=sum(t). CE_row = -dot + (m + log s) * ts. Mean via atomicAdd/N.
__global__ __launch_bounds__(256)
void ce_row_kernel(const float* __restrict__ pred,
                   const float* __restrict__ targ,
                   float* __restrict__ out) {
    const int row = blockIdx.x;
    const int tid = threadIdx.x;
    const float4* p = (const float4*)(pred + (size_t)row * C_COLS);
    const float4* t = (const float4*)(targ + (size_t)row * C_COLS);

    float m   = -INFINITY;
    float s   = 0.0f;
    float dot = 0.0f;
    float ts  = 0.0f;

    // 8000 float4 / 256 threads = 31.25 iterations (tid<64 do one extra).
    for (int i = tid; i < C4; i += 256) {
        float4 x  = p[i];
        float4 tv = t[i];
        float mx = fmaxf(fmaxf(x.x, x.y), fmaxf(x.z, x.w));
        if (mx > m) {                 // rare after warm-up: ~log(C) hits/row
            s *= __expf(m - mx);      // m=-inf first time: s==0, 0*0==0 ok
            m = mx;
        }
        s += __expf(x.x - m) + __expf(x.y - m)
           + __expf(x.z - m) + __expf(x.w - m);
        dot = fmaf(tv.x, x.x, dot);
        dot = fmaf(tv.y, x.y, dot);
        dot = fmaf(tv.z, x.z, dot);
        dot = fmaf(tv.w, x.w, dot);
        ts += (tv.x + tv.y) + (tv.z + tv.w);
    }

    // Butterfly reduce across the 64-lane wave (all lanes active & finite).
    #pragma unroll
    for (int off = 32; off > 0; off >>= 1) {
        float om = __shfl_xor(m,   off);
        float os = __shfl_xor(s,   off);
        float od = __shfl_xor(dot, off);
        float ot = __shfl_xor(ts,  off);
        float nm = fmaxf(m, om);
        s = s * __expf(m - nm) + os * __expf(om - nm);
        m = nm;
        dot += od;
        ts  += ot;
    }

    // Combine the 4 waves through LDS.
    __shared__ float sm[4], ss[4], sd[4], st[4];
    const int wave = tid >> 6;
    const int lane = tid & 63;
    if (lane == 0) { sm[wave] = m; ss[wave] = s; sd[wave] = dot; st[wave] = ts; }
    __syncthreads();
    if (tid == 0) {
        m = sm[0]; s = ss[0]; dot = sd[0]; ts = st[0];
        #pragma unroll
        for (int w = 1; w < 4; ++w) {
            float om = sm[w], os = ss[w];
            float nm = fmaxf(m, om);
            s = s * __expf(m - nm) + os * __expf(om - nm);
            m = nm;
            dot += sd[w];
            ts  += st[w];
        }
        float ce = -dot + (m + __logf(s)) * ts;
        atomicAdd(out, ce * (1.0f / N_ROWS));
    }
}

extern "C" void kernel_launch(void* const* d_in, const int* in_sizes, int n_in,
                              void* d_out, int out_size, void* d_ws, size_t ws_size,
                              hipStream_t stream) {
    const float* pred = (const float*)d_in[0];
    const float* targ = (const float*)d_in[1];
    float* out = (float*)d_out;

    // d_out is poisoned 0xAA before every timed launch — zero it on-stream.
    hipMemsetAsync(out, 0, sizeof(float), stream);
    ce_row_kernel<<<N_ROWS, 256, 0, stream>>>(pred, targ, out);
}